// Round 18
// baseline (300.174 us; speedup 1.0000x reference)
//
#include <hip/hip_runtime.h>
#include <hip/hip_bf16.h>

#define NN 100000
#define NE 3200000
#define INC 256
#define HID 64
#define OUTC 2
#define EPSV 1e-5f

#define NBUCK 128
#define BCAP  26000          // mean 25000, sigma ~157 -> +6.4 sigma margin
#define BIN_CHUNK 4096
#define BIN_K 16             // edges per thread (256 threads * 16 = 4096)
#define BIN_GRID ((NE + BIN_CHUNK - 1) / BIN_CHUNK)  // 782

#define NQUART 25000         // dst quarter (2 ch-halves x 4 dst-quarters = 8 cohorts)
#define SHALF 50000          // src half boundary

typedef short short8 __attribute__((ext_vector_type(8)));
typedef float f32x4 __attribute__((ext_vector_type(4)));

static __device__ __forceinline__ float bf2f(unsigned short u) {
    return __uint_as_float((unsigned)u << 16);
}
static __device__ __forceinline__ unsigned short f2bf(float f) {
    __hip_bfloat16 hb = __float2bfloat16(f);   // RNE
    return *(unsigned short*)&hb;
}

// ---------------- bin: partition edges into 128 dst-range buckets ----------------
// Packed entry: (dloc<<17) | src  (src < 2^17, dloc < 800 < 2^10).
__global__ __launch_bounds__(256) void bin_kernel(const int* __restrict__ src,
                                                  const int* __restrict__ dst,
                                                  int* __restrict__ gtail,
                                                  unsigned int* __restrict__ pbuf) {
    __shared__ int bcnt[NBUCK], bbase[NBUCK];
    int t = threadIdx.x;
    if (t < NBUCK) bcnt[t] = 0;
    __syncthreads();
    int base = blockIdx.x * BIN_CHUNK;
    int s[BIN_K], d[BIN_K], sl[BIN_K], bk[BIN_K];
#pragma unroll
    for (int r = 0; r < BIN_K; r++) {
        int i = base + r * 256 + t;
        bool v = i < NE;
        s[r] = v ? src[i] : 0;
        d[r] = v ? dst[i] : 0;
        bk[r] = (int)(((unsigned)d[r] * (unsigned)NBUCK) / (unsigned)NN);
        sl[r] = v ? atomicAdd(&bcnt[bk[r]], 1) : 0;
    }
    __syncthreads();
    if (t < NBUCK) bbase[t] = bcnt[t] ? atomicAdd(&gtail[t], bcnt[t]) : 0;
    __syncthreads();
#pragma unroll
    for (int r = 0; r < BIN_K; r++) {
        int i = base + r * 256 + t;
        if (i < NE) {
            int b = bk[r];
            int nbase = (b * NN + NBUCK - 1) >> 7;
            pbuf[(size_t)b * BCAP + bbase[b] + sl[r]] =
                ((unsigned)(d[r] - nbase) << 17) | (unsigned)s[r];
        }
    }
}

// ---------------- build: per-bucket {bucket-scan, histograms, rowptr+dinv+cnt0, segmented scatter} ----------------
// Row layout: [rowptr[d], rowptr[d]+cnt0[d]) = src<SHALF edges; rest = src>=SHALF.
__global__ __launch_bounds__(256) void build_kernel(const unsigned int* __restrict__ pbuf,
                                                    const int* __restrict__ gtail,
                                                    int* __restrict__ rowptr,
                                                    int* __restrict__ cnt0,
                                                    float* __restrict__ dinv,
                                                    int* __restrict__ e_src) {
    __shared__ int hS[800], h0S[800], rpS[800], f1S[800];
    __shared__ int wsum[4], wtot2[2], lbb[NBUCK];
    int b = blockIdx.x, t = threadIdx.x;
    int lane = t & 63, wave = t >> 6;
    // inline exclusive scan of gtail -> lbb (bucket global bases)
    int bv = 0, bs = 0;
    if (t < NBUCK) {
        bv = gtail[t];
        bs = bv;
        for (int o = 1; o < 64; o <<= 1) {
            int u = __shfl_up(bs, o);
            if (lane >= o) bs += u;
        }
        if (lane == 63) wtot2[wave] = bs;
    }
    __syncthreads();
    if (t < NBUCK) lbb[t] = bs - bv + ((t >= 64) ? wtot2[0] : 0);
    __syncthreads();
    int gb = lbb[b];

    int nb = (b * NN + NBUCK - 1) >> 7;
    int ne_ = ((b + 1) * NN + NBUCK - 1) >> 7;
    int range = ne_ - nb;
    for (int i = t; i < range; i += 256) { hS[i] = 0; h0S[i] = 0; }
    __syncthreads();
    int ecnt = gtail[b];
    const unsigned int* p = pbuf + (size_t)b * BCAP;
    for (int i = t; i < ecnt; i += 256) {
        unsigned int k = p[i];
        int loc = k >> 17;
        atomicAdd(&hS[loc], 1);
        if ((k & 0x1FFFFu) < SHALF) atomicAdd(&h0S[loc], 1);
    }
    __syncthreads();
    // scan of hS -> row starts; write rowptr, cnt0, dinv
    int idx = t * 4;
    int c0 = (idx + 0 < range) ? hS[idx + 0] : 0;
    int c1 = (idx + 1 < range) ? hS[idx + 1] : 0;
    int c2 = (idx + 2 < range) ? hS[idx + 2] : 0;
    int c3 = (idx + 3 < range) ? hS[idx + 3] : 0;
    int local = c0 + c1 + c2 + c3;
    int s = local;
    for (int o = 1; o < 64; o <<= 1) {
        int u = __shfl_up(s, o);
        if (lane >= o) s += u;
    }
    if (lane == 63) wsum[wave] = s;
    __syncthreads();
    if (t == 0) {
        int run = 0;
        for (int w = 0; w < 4; w++) { int x = wsum[w]; wsum[w] = run; run += x; }
    }
    __syncthreads();
    int start = wsum[wave] + (s - local);
    if (idx + 0 < range) { rpS[idx + 0] = start;                rowptr[nb + idx + 0] = gb + start;                cnt0[nb + idx + 0] = h0S[idx + 0]; dinv[nb + idx + 0] = rsqrtf((float)(c0 + 1)); }
    if (idx + 1 < range) { rpS[idx + 1] = start + c0;           rowptr[nb + idx + 1] = gb + start + c0;           cnt0[nb + idx + 1] = h0S[idx + 1]; dinv[nb + idx + 1] = rsqrtf((float)(c1 + 1)); }
    if (idx + 2 < range) { rpS[idx + 2] = start + c0 + c1;      rowptr[nb + idx + 2] = gb + start + c0 + c1;      cnt0[nb + idx + 2] = h0S[idx + 2]; dinv[nb + idx + 2] = rsqrtf((float)(c2 + 1)); }
    if (idx + 3 < range) { rpS[idx + 3] = start + c0 + c1 + c2; rowptr[nb + idx + 3] = gb + start + c0 + c1 + c2; cnt0[nb + idx + 3] = h0S[idx + 3]; dinv[nb + idx + 3] = rsqrtf((float)(c3 + 1)); }
    if (b == NBUCK - 1 && t == 0) rowptr[NN] = NE;
    __syncthreads();
    // zero fill counters: hS = f0, f1S = f1 (h0S stays = segment-0 count)
    for (int i = t; i < range; i += 256) { hS[i] = 0; f1S[i] = 0; }
    __syncthreads();
    for (int i = t; i < ecnt; i += 256) {
        unsigned int k = p[i];
        int loc = k >> 17;
        int srcn = (int)(k & 0x1FFFFu);
        int pos;
        if (srcn < SHALF) pos = gb + rpS[loc] + atomicAdd(&hS[loc], 1);
        else              pos = gb + rpS[loc] + h0S[loc] + atomicAdd(&f1S[loc], 1);
        e_src[pos] = srcn;
    }
}

// ---------------- wprep: W1 [256][64] fp32 -> Wtb [64][256] bf16 (transposed) ----------------
__global__ __launch_bounds__(256) void wprep_kernel(const float* __restrict__ W1,
                                                    unsigned short* __restrict__ Wtb) {
    int t = blockIdx.x * 256 + threadIdx.x;    // 16384 threads
    int c = t & 63;
    int k = t >> 6;
    Wtb[c * 256 + k] = f2bf(W1[k * 64 + c]);
}

// ---------------- GEMM1 (MFMA): xw1s[srcH][chH][50000][32] = bf16( dinv .* (x @ W1) ) ----------------
// LDS-staged x + W (R16 config). Sub-plane output: 3.2MB per (srcH,chH).
#define G1_ROWS 32
#define LDP 264
__global__ __launch_bounds__(256) void gemm1_kernel(const float* __restrict__ x,
                                                    const unsigned short* __restrict__ Wtb,
                                                    const float* __restrict__ dinv,
                                                    unsigned short* __restrict__ xw1s) {
    __shared__ unsigned short xt[G1_ROWS * LDP];   // 16896 B
    __shared__ unsigned short wt[HID * LDP];       // 33792 B
    int t = threadIdx.x;
    size_t base = (size_t)blockIdx.x * G1_ROWS;

    const float4* xg = (const float4*)(x + base * INC);
#pragma unroll
    for (int ii = 0; ii < 8; ii++) {
        int idx4 = ii * 256 + t;
        float4 v = xg[idx4];
        int f = idx4 * 4;
        int row = f >> 8, k = f & 255;
        ushort4 u;
        u.x = f2bf(v.x); u.y = f2bf(v.y); u.z = f2bf(v.z); u.w = f2bf(v.w);
        *(ushort4*)(xt + row * LDP + k) = u;
    }
    const int4* wsrc = (const int4*)Wtb;
#pragma unroll
    for (int ii = 0; ii < 8; ii++) {
        int idx4 = ii * 256 + t;
        int4 v = wsrc[idx4];
        int e16 = idx4 * 8;
        int c = e16 >> 8, k = e16 & 255;
        *(int4*)(wt + c * LDP + k) = v;
    }
    __syncthreads();

    int lane = t & 63;
    int wave = t >> 6;
    int l15 = lane & 15;
    int hi = lane >> 4;
    int rgrp = wave & 1;          // row group: 16 rows
    int cgrp = wave >> 1;         // channel half: 32 channels
    const unsigned short* ap = xt + (rgrp * 16 + l15) * LDP;
    const unsigned short* bp0 = wt + (cgrp * 32 + l15) * LDP;
    const unsigned short* bp1 = bp0 + 16 * LDP;
    f32x4 acc0 = {0.f, 0.f, 0.f, 0.f};
    f32x4 acc1 = {0.f, 0.f, 0.f, 0.f};
#pragma unroll
    for (int kk = 0; kk < 8; kk++) {
        int ko = kk * 32 + hi * 8;
        short8 a  = *(const short8*)(ap + ko);
        short8 b0 = *(const short8*)(bp0 + ko);
        short8 b1 = *(const short8*)(bp1 + ko);
        acc0 = __builtin_amdgcn_mfma_f32_16x16x32_bf16(a, b0, acc0, 0, 0, 0);
        acc1 = __builtin_amdgcn_mfma_f32_16x16x32_bf16(a, b1, acc1, 0, 0, 0);
    }
    // D: col = lane&15, row = (lane>>4)*4 + i
#pragma unroll
    for (int i = 0; i < 4; i++) {
        int grow = (int)base + rgrp * 16 + hi * 4 + i;
        float dv = dinv[grow];
        int sh = grow >= SHALF;
        unsigned short* ph = xw1s + ((size_t)(sh * 2 + cgrp)) * SHALF * 32
                                  + (size_t)(grow - sh * SHALF) * 32;
        ph[l15]      = f2bf(acc0[i] * dv);
        ph[l15 + 16] = f2bf(acc1[i] * dv);
    }
}

// ---------------- agg1a: pass 0 (src < SHALF), sub-plane L2-resident, raw partial to h1h ----------------
__global__ __launch_bounds__(256) void agg1a_kernel(const unsigned short* __restrict__ xw1s,
                                                    const int* __restrict__ rowptr,
                                                    const int* __restrict__ cnt0,
                                                    const int* __restrict__ e_src,
                                                    float* __restrict__ h1h) {
    int t = threadIdx.x;
    int lane = t & 63;
    int wave = t >> 6;
    int grp = lane >> 3;          // node group within wave (8 groups)
    int cl = lane & 7;            // ushort4 slot
    int cohort = blockIdx.x & 7;
    int h = cohort & 1;
    int dq = cohort >> 1;
    const ushort4* plane = (const ushort4*)(xw1s + (size_t)h * SHALF * 32);   // srcH=0
    float* hp = h1h + (size_t)h * NN * 32;
    int gid = ((blockIdx.x >> 3) * 4 + wave) * 8 + grp;
    int dlo = dq * NQUART;
    for (int d = dlo + gid; d < dlo + NQUART; d += 8192) {
        int beg = rowptr[d], end = beg + cnt0[d];
        float a0 = 0.f, a1 = 0.f, a2 = 0.f, a3 = 0.f;
        int e = beg;
        for (; e + 3 < end; e += 4) {
            int s0 = e_src[e], s1 = e_src[e + 1], s2 = e_src[e + 2], s3 = e_src[e + 3];
            ushort4 u0 = plane[(size_t)s0 * 8 + cl];
            ushort4 u1 = plane[(size_t)s1 * 8 + cl];
            ushort4 u2 = plane[(size_t)s2 * 8 + cl];
            ushort4 u3 = plane[(size_t)s3 * 8 + cl];
            a0 += bf2f(u0.x) + bf2f(u1.x) + bf2f(u2.x) + bf2f(u3.x);
            a1 += bf2f(u0.y) + bf2f(u1.y) + bf2f(u2.y) + bf2f(u3.y);
            a2 += bf2f(u0.z) + bf2f(u1.z) + bf2f(u2.z) + bf2f(u3.z);
            a3 += bf2f(u0.w) + bf2f(u1.w) + bf2f(u2.w) + bf2f(u3.w);
        }
        for (; e < end; e++) {
            int s = e_src[e];
            ushort4 u = plane[(size_t)s * 8 + cl];
            a0 += bf2f(u.x); a1 += bf2f(u.y); a2 += bf2f(u.z); a3 += bf2f(u.w);
        }
        f32x4 pv = {a0, a1, a2, a3};
        *(f32x4*)(hp + (size_t)d * 32 + cl * 4) = pv;
    }
}

// ---------------- agg1b: pass 1 (src >= SHALF) + partial + self-loop + finalize + stats ----------------
__global__ __launch_bounds__(256) void agg1b_kernel(const unsigned short* __restrict__ xw1s,
                                                    const int* __restrict__ rowptr,
                                                    const int* __restrict__ cnt0,
                                                    const int* __restrict__ e_src,
                                                    const float* __restrict__ dinv,
                                                    const float* __restrict__ b1,
                                                    float* __restrict__ h1h,
                                                    float* __restrict__ sums1) {
    __shared__ float lsum[4][32], lsq[4][32];
    int t = threadIdx.x;
    int lane = t & 63;
    int wave = t >> 6;
    int grp = lane >> 3;
    int cl = lane & 7;
    int cohort = blockIdx.x & 7;
    int h = cohort & 1;
    int dq = cohort >> 1;
    const ushort4* plane = (const ushort4*)(xw1s + (size_t)(2 + h) * SHALF * 32);  // srcH=1
    float* hp = h1h + (size_t)h * NN * 32;
    float bb0 = b1[h * 32 + cl * 4 + 0];
    float bb1 = b1[h * 32 + cl * 4 + 1];
    float bb2 = b1[h * 32 + cl * 4 + 2];
    float bb3 = b1[h * 32 + cl * 4 + 3];
    int gid = ((blockIdx.x >> 3) * 4 + wave) * 8 + grp;
    int dlo = dq * NQUART;
    float ss0 = 0.f, ss1 = 0.f, ss2 = 0.f, ss3 = 0.f;
    float sq0 = 0.f, sq1 = 0.f, sq2 = 0.f, sq3 = 0.f;
    for (int d = dlo + gid; d < dlo + NQUART; d += 8192) {
        int beg = rowptr[d] + cnt0[d], end = rowptr[d + 1];
        float a0 = 0.f, a1 = 0.f, a2 = 0.f, a3 = 0.f;
        int e = beg;
        for (; e + 3 < end; e += 4) {
            int s0 = e_src[e] - SHALF, s1 = e_src[e + 1] - SHALF;
            int s2 = e_src[e + 2] - SHALF, s3 = e_src[e + 3] - SHALF;
            ushort4 u0 = plane[(size_t)s0 * 8 + cl];
            ushort4 u1 = plane[(size_t)s1 * 8 + cl];
            ushort4 u2 = plane[(size_t)s2 * 8 + cl];
            ushort4 u3 = plane[(size_t)s3 * 8 + cl];
            a0 += bf2f(u0.x) + bf2f(u1.x) + bf2f(u2.x) + bf2f(u3.x);
            a1 += bf2f(u0.y) + bf2f(u1.y) + bf2f(u2.y) + bf2f(u3.y);
            a2 += bf2f(u0.z) + bf2f(u1.z) + bf2f(u2.z) + bf2f(u3.z);
            a3 += bf2f(u0.w) + bf2f(u1.w) + bf2f(u2.w) + bf2f(u3.w);
        }
        for (; e < end; e++) {
            int s = e_src[e] - SHALF;
            ushort4 u = plane[(size_t)s * 8 + cl];
            a0 += bf2f(u.x); a1 += bf2f(u.y); a2 += bf2f(u.z); a3 += bf2f(u.w);
        }
        // partial from pass 0
        f32x4 pv = *(const f32x4*)(hp + (size_t)d * 32 + cl * 4);
        // self-loop
        int dsh = d >= SHALF;
        const ushort4* sp = (const ushort4*)(xw1s + (size_t)(dsh * 2 + h) * SHALF * 32);
        ushort4 us = sp[(size_t)(d - dsh * SHALF) * 8 + cl];
        float dv = dinv[d];
        float h0 = (pv[0] + a0 + bf2f(us.x)) * dv + bb0;
        float h1v = (pv[1] + a1 + bf2f(us.y)) * dv + bb1;
        float h2 = (pv[2] + a2 + bf2f(us.z)) * dv + bb2;
        float h3 = (pv[3] + a3 + bf2f(us.w)) * dv + bb3;
        f32x4 hv = {h0, h1v, h2, h3};
        *(f32x4*)(hp + (size_t)d * 32 + cl * 4) = hv;
        ss0 += h0; sq0 += h0 * h0;
        ss1 += h1v; sq1 += h1v * h1v;
        ss2 += h2; sq2 += h2 * h2;
        ss3 += h3; sq3 += h3 * h3;
    }
#pragma unroll
    for (int o = 8; o < 64; o <<= 1) {
        ss0 += __shfl_xor(ss0, o); sq0 += __shfl_xor(sq0, o);
        ss1 += __shfl_xor(ss1, o); sq1 += __shfl_xor(sq1, o);
        ss2 += __shfl_xor(ss2, o); sq2 += __shfl_xor(sq2, o);
        ss3 += __shfl_xor(ss3, o); sq3 += __shfl_xor(sq3, o);
    }
    if (grp == 0) {
        lsum[wave][cl * 4 + 0] = ss0; lsq[wave][cl * 4 + 0] = sq0;
        lsum[wave][cl * 4 + 1] = ss1; lsq[wave][cl * 4 + 1] = sq1;
        lsum[wave][cl * 4 + 2] = ss2; lsq[wave][cl * 4 + 2] = sq2;
        lsum[wave][cl * 4 + 3] = ss3; lsq[wave][cl * 4 + 3] = sq3;
    }
    __syncthreads();
    if (t < 32) {
        float S = lsum[0][t] + lsum[1][t] + lsum[2][t] + lsum[3][t];
        float Q = lsq[0][t] + lsq[1][t] + lsq[2][t] + lsq[3][t];
        atomicAdd(&sums1[h * 32 + t], S);
        atomicAdd(&sums1[64 + h * 32 + t], Q);
    }
}

// ---------------- gemm2: xw2' = dinv .* (relu(BN1(h1)) @ W2) ----------------
__global__ __launch_bounds__(256) void gemm2_kernel(const float* __restrict__ h1h,
                                                    const float* __restrict__ sums1,
                                                    const float* __restrict__ g1,
                                                    const float* __restrict__ be1,
                                                    const float* __restrict__ W2,
                                                    const float* __restrict__ dinv,
                                                    float* __restrict__ xw2) {
    int lane = threadIdx.x & 63;
    int row = blockIdx.x * 4 + (threadIdx.x >> 6);
    if (row >= NN) return;
    int c = lane;
    const float invn = 1.0f / (float)NN;
    float mu = sums1[c] * invn;
    float var = sums1[64 + c] * invn - mu * mu;
    float sc = g1[c] * rsqrtf(var + EPSV);
    float sh = be1[c] - mu * sc;
    float hv = h1h[(size_t)(c >> 5) * NN * 32 + (size_t)row * 32 + (c & 31)] * sc + sh;
    hv = fmaxf(hv, 0.f);
    float p0 = hv * W2[c * 2 + 0];
    float p1 = hv * W2[c * 2 + 1];
    for (int o = 32; o; o >>= 1) {
        p0 += __shfl_xor(p0, o);
        p1 += __shfl_xor(p1, o);
    }
    if (lane == 0) {
        float dv = dinv[row];
        xw2[(size_t)row * 2 + 0] = p0 * dv;
        xw2[(size_t)row * 2 + 1] = p1 * dv;
    }
}

// ---------------- agg2: 8-lane group per node, banked stats ----------------
__global__ __launch_bounds__(256) void agg2_kernel(const float* __restrict__ xw2,
                                                   const int* __restrict__ rowptr,
                                                   const int* __restrict__ e_src,
                                                   const float* __restrict__ dinv,
                                                   const float* __restrict__ b2,
                                                   float* __restrict__ z2,
                                                   float* __restrict__ sums2) {
    __shared__ float red[4][4];
    int t = threadIdx.x;
    int lane = t & 63;
    int wave = t >> 6;
    int gl = lane & 7;                       // lane within node-group
    int d = blockIdx.x * 32 + (t >> 3);      // grid sized so d < NN always
    int beg = rowptr[d], end = rowptr[d + 1];
    float a0 = 0.f, a1 = 0.f;
    int e = beg + gl;
    for (; e + 24 < end; e += 32) {          // 4 independent gathers in flight
        int s0 = e_src[e], s1 = e_src[e + 8], s2 = e_src[e + 16], s3 = e_src[e + 24];
        float2 v0 = *(const float2*)(xw2 + (size_t)s0 * 2);
        float2 v1 = *(const float2*)(xw2 + (size_t)s1 * 2);
        float2 v2 = *(const float2*)(xw2 + (size_t)s2 * 2);
        float2 v3 = *(const float2*)(xw2 + (size_t)s3 * 2);
        a0 += v0.x + v1.x + v2.x + v3.x;
        a1 += v0.y + v1.y + v2.y + v3.y;
    }
    for (; e < end; e += 8) {
        int s = e_src[e];
        float2 v = *(const float2*)(xw2 + (size_t)s * 2);
        a0 += v.x;
        a1 += v.y;
    }
    if (gl == 0) {                           // self-loop
        float2 sf = *(const float2*)(xw2 + (size_t)d * 2);
        a0 += sf.x;
        a1 += sf.y;
    }
    a0 += __shfl_xor(a0, 1); a1 += __shfl_xor(a1, 1);
    a0 += __shfl_xor(a0, 2); a1 += __shfl_xor(a1, 2);
    a0 += __shfl_xor(a0, 4); a1 += __shfl_xor(a1, 4);
    float dv = dinv[d];
    float z0 = a0 * dv + b2[0];
    float z1 = a1 * dv + b2[1];
    if (gl == 0) *(float2*)(z2 + (size_t)d * 2) = make_float2(z0, z1);
    float s0 = (gl == 0) ? z0 : 0.f;
    float s1 = (gl == 0) ? z1 : 0.f;
    float q0 = (gl == 0) ? z0 * z0 : 0.f;
    float q1 = (gl == 0) ? z1 * z1 : 0.f;
    for (int o = 8; o < 64; o <<= 1) {
        s0 += __shfl_xor(s0, o); s1 += __shfl_xor(s1, o);
        q0 += __shfl_xor(q0, o); q1 += __shfl_xor(q1, o);
    }
    if (lane == 0) { red[wave][0] = s0; red[wave][1] = s1; red[wave][2] = q0; red[wave][3] = q1; }
    __syncthreads();
    if (t < 4) {
        float v = red[0][t] + red[1][t] + red[2][t] + red[3][t];
        atomicAdd(&sums2[(blockIdx.x & 7) * 4 + t], v);   // 8 banks
    }
}

// ---------------- decoder: out = BN2(z2) @ Wd + bd (sums2 banked [8][4]) ----------------
__global__ __launch_bounds__(256) void decoder_kernel(const float* __restrict__ z2,
                                                      const float* __restrict__ sums2,
                                                      const float* __restrict__ g2,
                                                      const float* __restrict__ be2,
                                                      const float* __restrict__ Wd,
                                                      const float* __restrict__ bd,
                                                      float* __restrict__ out) {
    int g = blockIdx.x * 256 + threadIdx.x;
    int row = g >> 6;
    int c4 = (g & 63) * 4;
    float t0 = 0.f, t1 = 0.f, t2 = 0.f, t3 = 0.f;
#pragma unroll
    for (int bk = 0; bk < 8; bk++) {
        t0 += sums2[bk * 4 + 0]; t1 += sums2[bk * 4 + 1];
        t2 += sums2[bk * 4 + 2]; t3 += sums2[bk * 4 + 3];
    }
    const float invn = 1.0f / (float)NN;
    float mu0 = t0 * invn, mu1 = t1 * invn;
    float v0 = t2 * invn - mu0 * mu0;
    float v1 = t3 * invn - mu1 * mu1;
    float sc0 = g2[0] * rsqrtf(v0 + EPSV), sh0 = be2[0] - mu0 * sc0;
    float sc1 = g2[1] * rsqrtf(v1 + EPSV), sh1 = be2[1] - mu1 * sc1;
    float zb0 = z2[(size_t)row * 2 + 0] * sc0 + sh0;
    float zb1 = z2[(size_t)row * 2 + 1] * sc1 + sh1;
    float4 w0 = *(const float4*)(Wd + c4);
    float4 w1 = *(const float4*)(Wd + INC + c4);
    float4 bb = *(const float4*)(bd + c4);
    float4 o;
    o.x = zb0 * w0.x + zb1 * w1.x + bb.x;
    o.y = zb0 * w0.y + zb1 * w1.y + bb.y;
    o.z = zb0 * w0.z + zb1 * w1.z + bb.z;
    o.w = zb0 * w0.w + zb1 * w1.w + bb.w;
    *(float4*)(out + (size_t)row * INC + c4) = o;
}

// ---------------- launch ----------------
static inline size_t align256(size_t x) { return (x + 255) & ~(size_t)255; }

extern "C" void kernel_launch(void* const* d_in, const int* in_sizes, int n_in,
                              void* d_out, int out_size, void* d_ws, size_t ws_size,
                              hipStream_t stream) {
    const float* x  = (const float*)d_in[0];
    const int*   ei = (const int*)d_in[1];     // [2, E] int32
    const float* W1 = (const float*)d_in[2];
    const float* b1 = (const float*)d_in[3];
    const float* g1 = (const float*)d_in[4];
    const float* be1 = (const float*)d_in[5];
    const float* W2 = (const float*)d_in[6];
    const float* b2 = (const float*)d_in[7];
    const float* g2 = (const float*)d_in[8];
    const float* be2 = (const float*)d_in[9];
    const float* Wd = (const float*)d_in[10];
    const float* bd = (const float*)d_in[11];
    float* out = (float*)d_out;

    const int* src = ei;
    const int* dst = ei + NE;

    char* ws = (char*)d_ws;
    size_t off = 0;
    int* gtail = (int*)(ws + off);      off = align256(off + NBUCK * 4);
    float* sums1 = (float*)(ws + off);  off = align256(off + 128 * 4);
    float* sums2 = (float*)(ws + off);  off = align256(off + 32 * 4);
    size_t zero_bytes = off;
    int* rowptr = (int*)(ws + off);     off = align256(off + (NN + 1) * 4);
    int* cnt0 = (int*)(ws + off);       off = align256(off + NN * 4);
    float* dinv = (float*)(ws + off);   off = align256(off + NN * 4);
    unsigned short* Wtb = (unsigned short*)(ws + off); off = align256(off + (size_t)HID * INC * 2);
    unsigned int* pbuf = (unsigned int*)(ws + off); off = align256(off + (size_t)NBUCK * BCAP * 4 + 4096);
    int* e_src = (int*)(ws + off);      off = align256(off + (size_t)NE * 4 + 64);
    unsigned short* xw1s = (unsigned short*)(ws + off); off = align256(off + (size_t)NN * HID * 2);
    float* h1h = (float*)(ws + off);    off = align256(off + (size_t)NN * HID * 4);
    float* xw2 = (float*)(ws + off);    off = align256(off + (size_t)NN * 2 * 4);
    float* z2 = (float*)(ws + off);     off = align256(off + (size_t)NN * 2 * 4);
    (void)ws_size; (void)in_sizes; (void)n_in; (void)out_size;

    hipMemsetAsync(d_ws, 0, zero_bytes, stream);

    bin_kernel<<<BIN_GRID, 256, 0, stream>>>(src, dst, gtail, pbuf);
    build_kernel<<<NBUCK, 256, 0, stream>>>(pbuf, gtail, rowptr, cnt0, dinv, e_src);
    wprep_kernel<<<64, 256, 0, stream>>>(W1, Wtb);
    gemm1_kernel<<<NN / G1_ROWS, 256, 0, stream>>>(x, Wtb, dinv, xw1s);
    agg1a_kernel<<<2048, 256, 0, stream>>>(xw1s, rowptr, cnt0, e_src, h1h);
    agg1b_kernel<<<2048, 256, 0, stream>>>(xw1s, rowptr, cnt0, e_src, dinv, b1, h1h, sums1);
    gemm2_kernel<<<(NN + 3) / 4, 256, 0, stream>>>(h1h, sums1, g1, be1, W2, dinv, xw2);
    agg2_kernel<<<NN * 8 / 256, 256, 0, stream>>>(xw2, rowptr, e_src, dinv, b2, z2, sums2);
    decoder_kernel<<<(NN * HID) / 256, 256, 0, stream>>>(z2, sums2, g2, be2, Wd, bd, out);
}

// Round 19
// 270.780 us; speedup vs baseline: 1.1086x; 1.1086x over previous
//
#include <hip/hip_runtime.h>
#include <hip/hip_bf16.h>

#define NN 100000
#define NE 3200000
#define INC 256
#define HID 64
#define OUTC 2
#define EPSV 1e-5f

#define NBUCK 128
#define BCAP  26000          // mean 25000, sigma ~157 -> +6.4 sigma margin
#define BIN_CHUNK 4096
#define BIN_K 16             // edges per thread (256 threads * 16 = 4096)
#define BIN_GRID ((NE + BIN_CHUNK - 1) / BIN_CHUNK)  // 782

#define NQUART 25000         // dst quarter (2 ch-halves x 4 dst-quarters = 8 cohorts)
#define SHALF 50000          // src half boundary

typedef short short8 __attribute__((ext_vector_type(8)));
typedef float f32x4 __attribute__((ext_vector_type(4)));

static __device__ __forceinline__ float bf2f(unsigned short u) {
    return __uint_as_float((unsigned)u << 16);
}
static __device__ __forceinline__ unsigned short f2bf(float f) {
    __hip_bfloat16 hb = __float2bfloat16(f);   // RNE
    return *(unsigned short*)&hb;
}

// ---------------- bin: partition edges into 128 dst-range buckets ----------------
// Packed entry: (dloc<<17) | src  (src < 2^17, dloc < 800 < 2^10).
__global__ __launch_bounds__(256) void bin_kernel(const int* __restrict__ src,
                                                  const int* __restrict__ dst,
                                                  int* __restrict__ gtail,
                                                  unsigned int* __restrict__ pbuf) {
    __shared__ int bcnt[NBUCK], bbase[NBUCK];
    int t = threadIdx.x;
    if (t < NBUCK) bcnt[t] = 0;
    __syncthreads();
    int base = blockIdx.x * BIN_CHUNK;
    int s[BIN_K], d[BIN_K], sl[BIN_K], bk[BIN_K];
#pragma unroll
    for (int r = 0; r < BIN_K; r++) {
        int i = base + r * 256 + t;
        bool v = i < NE;
        s[r] = v ? src[i] : 0;
        d[r] = v ? dst[i] : 0;
        bk[r] = (int)(((unsigned)d[r] * (unsigned)NBUCK) / (unsigned)NN);
        sl[r] = v ? atomicAdd(&bcnt[bk[r]], 1) : 0;
    }
    __syncthreads();
    if (t < NBUCK) bbase[t] = bcnt[t] ? atomicAdd(&gtail[t], bcnt[t]) : 0;
    __syncthreads();
#pragma unroll
    for (int r = 0; r < BIN_K; r++) {
        int i = base + r * 256 + t;
        if (i < NE) {
            int b = bk[r];
            int nbase = (b * NN + NBUCK - 1) >> 7;
            pbuf[(size_t)b * BCAP + bbase[b] + sl[r]] =
                ((unsigned)(d[r] - nbase) << 17) | (unsigned)s[r];
        }
    }
}

// ---------------- build: per-bucket {bucket-scan, paired histogram, rowptr+dinv+cnt0, seg scatter} ----------------
// Paired counters h2[2*loc+seg]: ONE branch-free LDS atomic per edge per pass.
// segbase[2*loc+seg] precomputed -> scatter = 1 LDS read + 1 LDS atomic.
// Per-edge loops unrolled x4 for latency cover at 128-block occupancy.
__global__ __launch_bounds__(256) void build_kernel(const unsigned int* __restrict__ pbuf,
                                                    const int* __restrict__ gtail,
                                                    int* __restrict__ rowptr,
                                                    int* __restrict__ cnt0,
                                                    float* __restrict__ dinv,
                                                    int* __restrict__ e_src) {
    __shared__ int h2[1600], segbase[1600], fill[1600];
    __shared__ int wsum[4], wtot2[2], lbb[NBUCK];
    int b = blockIdx.x, t = threadIdx.x;
    int lane = t & 63, wave = t >> 6;
    // inline exclusive scan of gtail -> lbb (bucket global bases)
    int bv = 0, bs = 0;
    if (t < NBUCK) {
        bv = gtail[t];
        bs = bv;
        for (int o = 1; o < 64; o <<= 1) {
            int u = __shfl_up(bs, o);
            if (lane >= o) bs += u;
        }
        if (lane == 63) wtot2[wave] = bs;
    }
    __syncthreads();
    if (t < NBUCK) lbb[t] = bs - bv + ((t >= 64) ? wtot2[0] : 0);
    __syncthreads();
    int gb = lbb[b];

    int nb = (b * NN + NBUCK - 1) >> 7;
    int ne_ = ((b + 1) * NN + NBUCK - 1) >> 7;
    int range = ne_ - nb;
    for (int i = t; i < range * 2; i += 256) h2[i] = 0;
    __syncthreads();
    int ecnt = gtail[b];
    const unsigned int* p = pbuf + (size_t)b * BCAP;
    // hist pass: 1 branch-free atomic/edge, unroll x4
    {
        int i = t;
        for (; i + 768 < ecnt; i += 1024) {
            unsigned int k0 = p[i], k1 = p[i + 256], k2 = p[i + 512], k3 = p[i + 768];
            int a0 = ((k0 >> 17) << 1) | ((k0 & 0x1FFFFu) >= SHALF);
            int a1 = ((k1 >> 17) << 1) | ((k1 & 0x1FFFFu) >= SHALF);
            int a2 = ((k2 >> 17) << 1) | ((k2 & 0x1FFFFu) >= SHALF);
            int a3 = ((k3 >> 17) << 1) | ((k3 & 0x1FFFFu) >= SHALF);
            atomicAdd(&h2[a0], 1);
            atomicAdd(&h2[a1], 1);
            atomicAdd(&h2[a2], 1);
            atomicAdd(&h2[a3], 1);
        }
        for (; i < ecnt; i += 256) {
            unsigned int k = p[i];
            atomicAdd(&h2[((k >> 17) << 1) | ((k & 0x1FFFFu) >= SHALF)], 1);
        }
    }
    __syncthreads();
    // scan of row totals -> row starts; write rowptr, cnt0, dinv, segbase
    int idx = t * 4;
    int t0 = (idx + 0 < range) ? h2[(idx + 0) * 2] + h2[(idx + 0) * 2 + 1] : 0;
    int t1 = (idx + 1 < range) ? h2[(idx + 1) * 2] + h2[(idx + 1) * 2 + 1] : 0;
    int t2 = (idx + 2 < range) ? h2[(idx + 2) * 2] + h2[(idx + 2) * 2 + 1] : 0;
    int t3 = (idx + 3 < range) ? h2[(idx + 3) * 2] + h2[(idx + 3) * 2 + 1] : 0;
    int local = t0 + t1 + t2 + t3;
    int s = local;
    for (int o = 1; o < 64; o <<= 1) {
        int u = __shfl_up(s, o);
        if (lane >= o) s += u;
    }
    if (lane == 63) wsum[wave] = s;
    __syncthreads();
    if (t == 0) {
        int run = 0;
        for (int w = 0; w < 4; w++) { int x = wsum[w]; wsum[w] = run; run += x; }
    }
    __syncthreads();
    int start = wsum[wave] + (s - local);
#pragma unroll
    for (int j = 0; j < 4; j++) {
        int loc = idx + j;
        if (loc < range) {
            int c0s = h2[loc * 2];
            segbase[loc * 2]     = start;
            segbase[loc * 2 + 1] = start + c0s;
            rowptr[nb + loc] = gb + start;
            cnt0[nb + loc] = c0s;
            int tot = c0s + h2[loc * 2 + 1];
            dinv[nb + loc] = rsqrtf((float)(tot + 1));
            start += tot;
        }
    }
    if (b == NBUCK - 1 && t == 0) rowptr[NN] = NE;
    __syncthreads();
    for (int i = t; i < range * 2; i += 256) fill[i] = 0;
    __syncthreads();
    // scatter pass: 1 LDS read + 1 atomic/edge, unroll x4
    {
        int i = t;
        for (; i + 768 < ecnt; i += 1024) {
            unsigned int k0 = p[i], k1 = p[i + 256], k2 = p[i + 512], k3 = p[i + 768];
            int s0 = (int)(k0 & 0x1FFFFu), s1 = (int)(k1 & 0x1FFFFu);
            int s2 = (int)(k2 & 0x1FFFFu), s3 = (int)(k3 & 0x1FFFFu);
            int a0 = ((k0 >> 17) << 1) | (s0 >= SHALF);
            int a1 = ((k1 >> 17) << 1) | (s1 >= SHALF);
            int a2 = ((k2 >> 17) << 1) | (s2 >= SHALF);
            int a3 = ((k3 >> 17) << 1) | (s3 >= SHALF);
            int p0 = gb + segbase[a0] + atomicAdd(&fill[a0], 1);
            int p1 = gb + segbase[a1] + atomicAdd(&fill[a1], 1);
            int p2 = gb + segbase[a2] + atomicAdd(&fill[a2], 1);
            int p3 = gb + segbase[a3] + atomicAdd(&fill[a3], 1);
            e_src[p0] = s0;
            e_src[p1] = s1;
            e_src[p2] = s2;
            e_src[p3] = s3;
        }
        for (; i < ecnt; i += 256) {
            unsigned int k = p[i];
            int sn = (int)(k & 0x1FFFFu);
            int a = ((k >> 17) << 1) | (sn >= SHALF);
            int pos = gb + segbase[a] + atomicAdd(&fill[a], 1);
            e_src[pos] = sn;
        }
    }
}

// ---------------- wprep: W1 [256][64] fp32 -> Wtb [64][256] bf16 (transposed) ----------------
__global__ __launch_bounds__(256) void wprep_kernel(const float* __restrict__ W1,
                                                    unsigned short* __restrict__ Wtb) {
    int t = blockIdx.x * 256 + threadIdx.x;    // 16384 threads
    int c = t & 63;
    int k = t >> 6;
    Wtb[c * 256 + k] = f2bf(W1[k * 64 + c]);
}

// ---------------- GEMM1 (MFMA): xw1s[srcH][chH][50000][32] = bf16( dinv .* (x @ W1) ) ----------------
#define G1_ROWS 32
#define LDP 264
__global__ __launch_bounds__(256) void gemm1_kernel(const float* __restrict__ x,
                                                    const unsigned short* __restrict__ Wtb,
                                                    const float* __restrict__ dinv,
                                                    unsigned short* __restrict__ xw1s) {
    __shared__ unsigned short xt[G1_ROWS * LDP];   // 16896 B
    __shared__ unsigned short wt[HID * LDP];       // 33792 B
    int t = threadIdx.x;
    size_t base = (size_t)blockIdx.x * G1_ROWS;

    const float4* xg = (const float4*)(x + base * INC);
#pragma unroll
    for (int ii = 0; ii < 8; ii++) {
        int idx4 = ii * 256 + t;
        float4 v = xg[idx4];
        int f = idx4 * 4;
        int row = f >> 8, k = f & 255;
        ushort4 u;
        u.x = f2bf(v.x); u.y = f2bf(v.y); u.z = f2bf(v.z); u.w = f2bf(v.w);
        *(ushort4*)(xt + row * LDP + k) = u;
    }
    const int4* wsrc = (const int4*)Wtb;
#pragma unroll
    for (int ii = 0; ii < 8; ii++) {
        int idx4 = ii * 256 + t;
        int4 v = wsrc[idx4];
        int e16 = idx4 * 8;
        int c = e16 >> 8, k = e16 & 255;
        *(int4*)(wt + c * LDP + k) = v;
    }
    __syncthreads();

    int lane = t & 63;
    int wave = t >> 6;
    int l15 = lane & 15;
    int hi = lane >> 4;
    int rgrp = wave & 1;          // row group: 16 rows
    int cgrp = wave >> 1;         // channel half: 32 channels
    const unsigned short* ap = xt + (rgrp * 16 + l15) * LDP;
    const unsigned short* bp0 = wt + (cgrp * 32 + l15) * LDP;
    const unsigned short* bp1 = bp0 + 16 * LDP;
    f32x4 acc0 = {0.f, 0.f, 0.f, 0.f};
    f32x4 acc1 = {0.f, 0.f, 0.f, 0.f};
#pragma unroll
    for (int kk = 0; kk < 8; kk++) {
        int ko = kk * 32 + hi * 8;
        short8 a  = *(const short8*)(ap + ko);
        short8 b0 = *(const short8*)(bp0 + ko);
        short8 b1 = *(const short8*)(bp1 + ko);
        acc0 = __builtin_amdgcn_mfma_f32_16x16x32_bf16(a, b0, acc0, 0, 0, 0);
        acc1 = __builtin_amdgcn_mfma_f32_16x16x32_bf16(a, b1, acc1, 0, 0, 0);
    }
    // D: col = lane&15, row = (lane>>4)*4 + i
#pragma unroll
    for (int i = 0; i < 4; i++) {
        int grow = (int)base + rgrp * 16 + hi * 4 + i;
        float dv = dinv[grow];
        int sh = grow >= SHALF;
        unsigned short* ph = xw1s + ((size_t)(sh * 2 + cgrp)) * SHALF * 32
                                  + (size_t)(grow - sh * SHALF) * 32;
        ph[l15]      = f2bf(acc0[i] * dv);
        ph[l15 + 16] = f2bf(acc1[i] * dv);
    }
}

// ---------------- agg1a: pass 0 (src < SHALF), sub-plane L2-resident, raw partial to h1h ----------------
__global__ __launch_bounds__(256) void agg1a_kernel(const unsigned short* __restrict__ xw1s,
                                                    const int* __restrict__ rowptr,
                                                    const int* __restrict__ cnt0,
                                                    const int* __restrict__ e_src,
                                                    float* __restrict__ h1h) {
    int t = threadIdx.x;
    int lane = t & 63;
    int wave = t >> 6;
    int grp = lane >> 3;          // node group within wave (8 groups)
    int cl = lane & 7;            // ushort4 slot
    int cohort = blockIdx.x & 7;
    int h = cohort & 1;
    int dq = cohort >> 1;
    const ushort4* plane = (const ushort4*)(xw1s + (size_t)h * SHALF * 32);   // srcH=0
    float* hp = h1h + (size_t)h * NN * 32;
    int gid = ((blockIdx.x >> 3) * 4 + wave) * 8 + grp;
    int dlo = dq * NQUART;
    for (int d = dlo + gid; d < dlo + NQUART; d += 8192) {
        int beg = rowptr[d], end = beg + cnt0[d];
        float a0 = 0.f, a1 = 0.f, a2 = 0.f, a3 = 0.f;
        int e = beg;
        for (; e + 3 < end; e += 4) {
            int s0 = e_src[e], s1 = e_src[e + 1], s2 = e_src[e + 2], s3 = e_src[e + 3];
            ushort4 u0 = plane[(size_t)s0 * 8 + cl];
            ushort4 u1 = plane[(size_t)s1 * 8 + cl];
            ushort4 u2 = plane[(size_t)s2 * 8 + cl];
            ushort4 u3 = plane[(size_t)s3 * 8 + cl];
            a0 += bf2f(u0.x) + bf2f(u1.x) + bf2f(u2.x) + bf2f(u3.x);
            a1 += bf2f(u0.y) + bf2f(u1.y) + bf2f(u2.y) + bf2f(u3.y);
            a2 += bf2f(u0.z) + bf2f(u1.z) + bf2f(u2.z) + bf2f(u3.z);
            a3 += bf2f(u0.w) + bf2f(u1.w) + bf2f(u2.w) + bf2f(u3.w);
        }
        for (; e < end; e++) {
            int s = e_src[e];
            ushort4 u = plane[(size_t)s * 8 + cl];
            a0 += bf2f(u.x); a1 += bf2f(u.y); a2 += bf2f(u.z); a3 += bf2f(u.w);
        }
        f32x4 pv = {a0, a1, a2, a3};
        *(f32x4*)(hp + (size_t)d * 32 + cl * 4) = pv;
    }
}

// ---------------- agg1b: pass 1 (src >= SHALF) + partial + self-loop + finalize + stats ----------------
__global__ __launch_bounds__(256) void agg1b_kernel(const unsigned short* __restrict__ xw1s,
                                                    const int* __restrict__ rowptr,
                                                    const int* __restrict__ cnt0,
                                                    const int* __restrict__ e_src,
                                                    const float* __restrict__ dinv,
                                                    const float* __restrict__ b1,
                                                    float* __restrict__ h1h,
                                                    float* __restrict__ sums1) {
    __shared__ float lsum[4][32], lsq[4][32];
    int t = threadIdx.x;
    int lane = t & 63;
    int wave = t >> 6;
    int grp = lane >> 3;
    int cl = lane & 7;
    int cohort = blockIdx.x & 7;
    int h = cohort & 1;
    int dq = cohort >> 1;
    const ushort4* plane = (const ushort4*)(xw1s + (size_t)(2 + h) * SHALF * 32);  // srcH=1
    float* hp = h1h + (size_t)h * NN * 32;
    float bb0 = b1[h * 32 + cl * 4 + 0];
    float bb1 = b1[h * 32 + cl * 4 + 1];
    float bb2 = b1[h * 32 + cl * 4 + 2];
    float bb3 = b1[h * 32 + cl * 4 + 3];
    int gid = ((blockIdx.x >> 3) * 4 + wave) * 8 + grp;
    int dlo = dq * NQUART;
    float ss0 = 0.f, ss1 = 0.f, ss2 = 0.f, ss3 = 0.f;
    float sq0 = 0.f, sq1 = 0.f, sq2 = 0.f, sq3 = 0.f;
    for (int d = dlo + gid; d < dlo + NQUART; d += 8192) {
        int beg = rowptr[d] + cnt0[d], end = rowptr[d + 1];
        float a0 = 0.f, a1 = 0.f, a2 = 0.f, a3 = 0.f;
        int e = beg;
        for (; e + 3 < end; e += 4) {
            int s0 = e_src[e] - SHALF, s1 = e_src[e + 1] - SHALF;
            int s2 = e_src[e + 2] - SHALF, s3 = e_src[e + 3] - SHALF;
            ushort4 u0 = plane[(size_t)s0 * 8 + cl];
            ushort4 u1 = plane[(size_t)s1 * 8 + cl];
            ushort4 u2 = plane[(size_t)s2 * 8 + cl];
            ushort4 u3 = plane[(size_t)s3 * 8 + cl];
            a0 += bf2f(u0.x) + bf2f(u1.x) + bf2f(u2.x) + bf2f(u3.x);
            a1 += bf2f(u0.y) + bf2f(u1.y) + bf2f(u2.y) + bf2f(u3.y);
            a2 += bf2f(u0.z) + bf2f(u1.z) + bf2f(u2.z) + bf2f(u3.z);
            a3 += bf2f(u0.w) + bf2f(u1.w) + bf2f(u2.w) + bf2f(u3.w);
        }
        for (; e < end; e++) {
            int s = e_src[e] - SHALF;
            ushort4 u = plane[(size_t)s * 8 + cl];
            a0 += bf2f(u.x); a1 += bf2f(u.y); a2 += bf2f(u.z); a3 += bf2f(u.w);
        }
        // partial from pass 0
        f32x4 pv = *(const f32x4*)(hp + (size_t)d * 32 + cl * 4);
        // self-loop
        int dsh = d >= SHALF;
        const ushort4* sp = (const ushort4*)(xw1s + (size_t)(dsh * 2 + h) * SHALF * 32);
        ushort4 us = sp[(size_t)(d - dsh * SHALF) * 8 + cl];
        float dv = dinv[d];
        float h0 = (pv[0] + a0 + bf2f(us.x)) * dv + bb0;
        float h1v = (pv[1] + a1 + bf2f(us.y)) * dv + bb1;
        float h2 = (pv[2] + a2 + bf2f(us.z)) * dv + bb2;
        float h3 = (pv[3] + a3 + bf2f(us.w)) * dv + bb3;
        f32x4 hv = {h0, h1v, h2, h3};
        *(f32x4*)(hp + (size_t)d * 32 + cl * 4) = hv;
        ss0 += h0; sq0 += h0 * h0;
        ss1 += h1v; sq1 += h1v * h1v;
        ss2 += h2; sq2 += h2 * h2;
        ss3 += h3; sq3 += h3 * h3;
    }
#pragma unroll
    for (int o = 8; o < 64; o <<= 1) {
        ss0 += __shfl_xor(ss0, o); sq0 += __shfl_xor(sq0, o);
        ss1 += __shfl_xor(ss1, o); sq1 += __shfl_xor(sq1, o);
        ss2 += __shfl_xor(ss2, o); sq2 += __shfl_xor(sq2, o);
        ss3 += __shfl_xor(ss3, o); sq3 += __shfl_xor(sq3, o);
    }
    if (grp == 0) {
        lsum[wave][cl * 4 + 0] = ss0; lsq[wave][cl * 4 + 0] = sq0;
        lsum[wave][cl * 4 + 1] = ss1; lsq[wave][cl * 4 + 1] = sq1;
        lsum[wave][cl * 4 + 2] = ss2; lsq[wave][cl * 4 + 2] = sq2;
        lsum[wave][cl * 4 + 3] = ss3; lsq[wave][cl * 4 + 3] = sq3;
    }
    __syncthreads();
    if (t < 32) {
        float S = lsum[0][t] + lsum[1][t] + lsum[2][t] + lsum[3][t];
        float Q = lsq[0][t] + lsq[1][t] + lsq[2][t] + lsq[3][t];
        atomicAdd(&sums1[h * 32 + t], S);
        atomicAdd(&sums1[64 + h * 32 + t], Q);
    }
}

// ---------------- gemm2: xw2' = dinv .* (relu(BN1(h1)) @ W2) ----------------
__global__ __launch_bounds__(256) void gemm2_kernel(const float* __restrict__ h1h,
                                                    const float* __restrict__ sums1,
                                                    const float* __restrict__ g1,
                                                    const float* __restrict__ be1,
                                                    const float* __restrict__ W2,
                                                    const float* __restrict__ dinv,
                                                    float* __restrict__ xw2) {
    int lane = threadIdx.x & 63;
    int row = blockIdx.x * 4 + (threadIdx.x >> 6);
    if (row >= NN) return;
    int c = lane;
    const float invn = 1.0f / (float)NN;
    float mu = sums1[c] * invn;
    float var = sums1[64 + c] * invn - mu * mu;
    float sc = g1[c] * rsqrtf(var + EPSV);
    float sh = be1[c] - mu * sc;
    float hv = h1h[(size_t)(c >> 5) * NN * 32 + (size_t)row * 32 + (c & 31)] * sc + sh;
    hv = fmaxf(hv, 0.f);
    float p0 = hv * W2[c * 2 + 0];
    float p1 = hv * W2[c * 2 + 1];
    for (int o = 32; o; o >>= 1) {
        p0 += __shfl_xor(p0, o);
        p1 += __shfl_xor(p1, o);
    }
    if (lane == 0) {
        float dv = dinv[row];
        xw2[(size_t)row * 2 + 0] = p0 * dv;
        xw2[(size_t)row * 2 + 1] = p1 * dv;
    }
}

// ---------------- agg2: 8-lane group per node, banked stats ----------------
__global__ __launch_bounds__(256) void agg2_kernel(const float* __restrict__ xw2,
                                                   const int* __restrict__ rowptr,
                                                   const int* __restrict__ e_src,
                                                   const float* __restrict__ dinv,
                                                   const float* __restrict__ b2,
                                                   float* __restrict__ z2,
                                                   float* __restrict__ sums2) {
    __shared__ float red[4][4];
    int t = threadIdx.x;
    int lane = t & 63;
    int wave = t >> 6;
    int gl = lane & 7;                       // lane within node-group
    int d = blockIdx.x * 32 + (t >> 3);      // grid sized so d < NN always
    int beg = rowptr[d], end = rowptr[d + 1];
    float a0 = 0.f, a1 = 0.f;
    int e = beg + gl;
    for (; e + 24 < end; e += 32) {          // 4 independent gathers in flight
        int s0 = e_src[e], s1 = e_src[e + 8], s2 = e_src[e + 16], s3 = e_src[e + 24];
        float2 v0 = *(const float2*)(xw2 + (size_t)s0 * 2);
        float2 v1 = *(const float2*)(xw2 + (size_t)s1 * 2);
        float2 v2 = *(const float2*)(xw2 + (size_t)s2 * 2);
        float2 v3 = *(const float2*)(xw2 + (size_t)s3 * 2);
        a0 += v0.x + v1.x + v2.x + v3.x;
        a1 += v0.y + v1.y + v2.y + v3.y;
    }
    for (; e < end; e += 8) {
        int s = e_src[e];
        float2 v = *(const float2*)(xw2 + (size_t)s * 2);
        a0 += v.x;
        a1 += v.y;
    }
    if (gl == 0) {                           // self-loop
        float2 sf = *(const float2*)(xw2 + (size_t)d * 2);
        a0 += sf.x;
        a1 += sf.y;
    }
    a0 += __shfl_xor(a0, 1); a1 += __shfl_xor(a1, 1);
    a0 += __shfl_xor(a0, 2); a1 += __shfl_xor(a1, 2);
    a0 += __shfl_xor(a0, 4); a1 += __shfl_xor(a1, 4);
    float dv = dinv[d];
    float z0 = a0 * dv + b2[0];
    float z1 = a1 * dv + b2[1];
    if (gl == 0) *(float2*)(z2 + (size_t)d * 2) = make_float2(z0, z1);
    float s0 = (gl == 0) ? z0 : 0.f;
    float s1 = (gl == 0) ? z1 : 0.f;
    float q0 = (gl == 0) ? z0 * z0 : 0.f;
    float q1 = (gl == 0) ? z1 * z1 : 0.f;
    for (int o = 8; o < 64; o <<= 1) {
        s0 += __shfl_xor(s0, o); s1 += __shfl_xor(s1, o);
        q0 += __shfl_xor(q0, o); q1 += __shfl_xor(q1, o);
    }
    if (lane == 0) { red[wave][0] = s0; red[wave][1] = s1; red[wave][2] = q0; red[wave][3] = q1; }
    __syncthreads();
    if (t < 4) {
        float v = red[0][t] + red[1][t] + red[2][t] + red[3][t];
        atomicAdd(&sums2[(blockIdx.x & 7) * 4 + t], v);   // 8 banks
    }
}

// ---------------- decoder: out = BN2(z2) @ Wd + bd (sums2 banked [8][4]) ----------------
__global__ __launch_bounds__(256) void decoder_kernel(const float* __restrict__ z2,
                                                      const float* __restrict__ sums2,
                                                      const float* __restrict__ g2,
                                                      const float* __restrict__ be2,
                                                      const float* __restrict__ Wd,
                                                      const float* __restrict__ bd,
                                                      float* __restrict__ out) {
    int g = blockIdx.x * 256 + threadIdx.x;
    int row = g >> 6;
    int c4 = (g & 63) * 4;
    float t0 = 0.f, t1 = 0.f, t2 = 0.f, t3 = 0.f;
#pragma unroll
    for (int bk = 0; bk < 8; bk++) {
        t0 += sums2[bk * 4 + 0]; t1 += sums2[bk * 4 + 1];
        t2 += sums2[bk * 4 + 2]; t3 += sums2[bk * 4 + 3];
    }
    const float invn = 1.0f / (float)NN;
    float mu0 = t0 * invn, mu1 = t1 * invn;
    float v0 = t2 * invn - mu0 * mu0;
    float v1 = t3 * invn - mu1 * mu1;
    float sc0 = g2[0] * rsqrtf(v0 + EPSV), sh0 = be2[0] - mu0 * sc0;
    float sc1 = g2[1] * rsqrtf(v1 + EPSV), sh1 = be2[1] - mu1 * sc1;
    float zb0 = z2[(size_t)row * 2 + 0] * sc0 + sh0;
    float zb1 = z2[(size_t)row * 2 + 1] * sc1 + sh1;
    float4 w0 = *(const float4*)(Wd + c4);
    float4 w1 = *(const float4*)(Wd + INC + c4);
    float4 bb = *(const float4*)(bd + c4);
    float4 o;
    o.x = zb0 * w0.x + zb1 * w1.x + bb.x;
    o.y = zb0 * w0.y + zb1 * w1.y + bb.y;
    o.z = zb0 * w0.z + zb1 * w1.z + bb.z;
    o.w = zb0 * w0.w + zb1 * w1.w + bb.w;
    *(float4*)(out + (size_t)row * INC + c4) = o;
}

// ---------------- launch ----------------
static inline size_t align256(size_t x) { return (x + 255) & ~(size_t)255; }

extern "C" void kernel_launch(void* const* d_in, const int* in_sizes, int n_in,
                              void* d_out, int out_size, void* d_ws, size_t ws_size,
                              hipStream_t stream) {
    const float* x  = (const float*)d_in[0];
    const int*   ei = (const int*)d_in[1];     // [2, E] int32
    const float* W1 = (const float*)d_in[2];
    const float* b1 = (const float*)d_in[3];
    const float* g1 = (const float*)d_in[4];
    const float* be1 = (const float*)d_in[5];
    const float* W2 = (const float*)d_in[6];
    const float* b2 = (const float*)d_in[7];
    const float* g2 = (const float*)d_in[8];
    const float* be2 = (const float*)d_in[9];
    const float* Wd = (const float*)d_in[10];
    const float* bd = (const float*)d_in[11];
    float* out = (float*)d_out;

    const int* src = ei;
    const int* dst = ei + NE;

    char* ws = (char*)d_ws;
    size_t off = 0;
    int* gtail = (int*)(ws + off);      off = align256(off + NBUCK * 4);
    float* sums1 = (float*)(ws + off);  off = align256(off + 128 * 4);
    float* sums2 = (float*)(ws + off);  off = align256(off + 32 * 4);
    size_t zero_bytes = off;
    int* rowptr = (int*)(ws + off);     off = align256(off + (NN + 1) * 4);
    int* cnt0 = (int*)(ws + off);       off = align256(off + NN * 4);
    float* dinv = (float*)(ws + off);   off = align256(off + NN * 4);
    unsigned short* Wtb = (unsigned short*)(ws + off); off = align256(off + (size_t)HID * INC * 2);
    unsigned int* pbuf = (unsigned int*)(ws + off); off = align256(off + (size_t)NBUCK * BCAP * 4 + 4096);
    int* e_src = (int*)(ws + off);      off = align256(off + (size_t)NE * 4 + 64);
    unsigned short* xw1s = (unsigned short*)(ws + off); off = align256(off + (size_t)NN * HID * 2);
    float* h1h = (float*)(ws + off);    off = align256(off + (size_t)NN * HID * 4);
    float* xw2 = (float*)(ws + off);    off = align256(off + (size_t)NN * 2 * 4);
    float* z2 = (float*)(ws + off);     off = align256(off + (size_t)NN * 2 * 4);
    (void)ws_size; (void)in_sizes; (void)n_in; (void)out_size;

    hipMemsetAsync(d_ws, 0, zero_bytes, stream);

    bin_kernel<<<BIN_GRID, 256, 0, stream>>>(src, dst, gtail, pbuf);
    build_kernel<<<NBUCK, 256, 0, stream>>>(pbuf, gtail, rowptr, cnt0, dinv, e_src);
    wprep_kernel<<<64, 256, 0, stream>>>(W1, Wtb);
    gemm1_kernel<<<NN / G1_ROWS, 256, 0, stream>>>(x, Wtb, dinv, xw1s);
    agg1a_kernel<<<2048, 256, 0, stream>>>(xw1s, rowptr, cnt0, e_src, h1h);
    agg1b_kernel<<<2048, 256, 0, stream>>>(xw1s, rowptr, cnt0, e_src, dinv, b1, h1h, sums1);
    gemm2_kernel<<<(NN + 3) / 4, 256, 0, stream>>>(h1h, sums1, g1, be1, W2, dinv, xw2);
    agg2_kernel<<<NN * 8 / 256, 256, 0, stream>>>(xw2, rowptr, e_src, dinv, b2, z2, sums2);
    decoder_kernel<<<(NN * HID) / 256, 256, 0, stream>>>(z2, sums2, g2, be2, Wd, bd, out);
}